// Round 1
// baseline (470.183 us; speedup 1.0000x reference)
//
#include <hip/hip_runtime.h>
#include <hip/hip_bf16.h>
#include <stdint.h>

// HQQ grouped GEMM, MI355X (gfx950).
// Strategy:
//   y[t,o] = sum_g scale[e,g,o] * S_g[t,o]  -  sum_g r[t,g]*zero[e,g,o]*scale[e,g,o]
//   where S_g = x_g @ Wq_g (Wq ints 0..15 exact in bf16), x split into bf16 hi+lo
//   planes (error ~2^-16 rel). Zero-term folded in as a 17th pseudo K-group:
//   A-cols [r_hi | r_hi | r_lo | 0], B-rows [-zs_hi | -zs_lo | -zs_hi | 0].
// prep kernel: x fp32 -> xhi/xlo bf16 planes (stride 1088 = 1024 + 64 pseudo cols)
//              + per-group rowsums baked into the pseudo cols.
// gemm kernel: BM=64 x BN=128, 4 waves (each 32x64), per-(expert,mtile,ntile)
//              grid with early exit; A via global_load_lds(16B); B reg-staged
//              int32->bf16 into transposed LDS [o][k] (stride 72, 16B-aligned);
//              mfma_f32_16x16x32_bf16; fp32 per-group scale pass on partials.

namespace {
constexpr int kE = 8;
constexpr int kIn = 1024;
constexpr int kOut = 2816;
constexpr int kGroups = 16;         // quant groups along IN (GS=64)
constexpr int kTok = 2048;
constexpr int kXStride = kIn + 64;  // 1088: x cols + pseudo-group cols
constexpr int kBM = 64;
constexpr int kBN = 128;
constexpr int kBTS = 72;            // Bt LDS row stride in elems (144 B, 16B-aligned)
constexpr int kNT = kOut / kBN;     // 22 n-tiles
}

typedef __attribute__((ext_vector_type(8))) short short8;
typedef __attribute__((ext_vector_type(4))) float f32x4;
typedef __attribute__((ext_vector_type(4))) int i32x4;
typedef __attribute__((ext_vector_type(4))) unsigned int u32x4;

static __device__ __forceinline__ uint32_t fbits(float f) {
  union { float f; uint32_t u; } v; v.f = f; return v.u;
}
static __device__ __forceinline__ unsigned short bf16_rne(float f) {
  uint32_t u = fbits(f);
  u += 0x7fffu + ((u >> 16) & 1u);
  return (unsigned short)(u >> 16);
}
static __device__ __forceinline__ float bf16_f(unsigned short h) {
  union { uint32_t u; float f; } v; v.u = ((uint32_t)h) << 16; return v.f;
}
static __device__ __forceinline__ void async_cp16(const void* g, void* l) {
  __builtin_amdgcn_global_load_lds(
      (const __attribute__((address_space(1))) unsigned int*)g,
      (__attribute__((address_space(3))) unsigned int*)l, 16, 0, 0);
}

// ---------------- prep: x -> bf16 hi/lo planes + group rowsums ----------------
__global__ __launch_bounds__(256) void hqq_prep(const float* __restrict__ x,
                                                unsigned short* __restrict__ xhi,
                                                unsigned short* __restrict__ xlo) {
  const int row = blockIdx.x;   // token
  const int tid = threadIdx.x;  // 256 threads, 4 floats each
  const f32x4 v = *(const f32x4*)(x + (size_t)row * kIn + tid * 4);
  unsigned long long hp = 0, lp = 0;
  float s = 0.f;
#pragma unroll
  for (int j = 0; j < 4; ++j) {
    float f = v[j];
    unsigned short h = bf16_rne(f);
    unsigned short l = bf16_rne(f - bf16_f(h));
    hp |= ((unsigned long long)h) << (16 * j);
    lp |= ((unsigned long long)l) << (16 * j);
    s += f;
  }
  *(unsigned long long*)(xhi + (size_t)row * kXStride + tid * 4) = hp;
  *(unsigned long long*)(xlo + (size_t)row * kXStride + tid * 4) = lp;
  // group rowsum: 16 consecutive lanes = 64 floats = one group
#pragma unroll
  for (int m = 1; m <= 8; m <<= 1) s += __shfl_xor(s, m, 64);
  if ((tid & 15) == 0) {
    const int g = tid >> 4;  // 0..15
    unsigned short rhi = bf16_rne(s);
    unsigned short rlo = bf16_rne(s - bf16_f(rhi));
    unsigned short* p = xhi + (size_t)row * kXStride + kIn;
    p[g] = rhi; p[16 + g] = rhi; p[32 + g] = rlo; p[48 + g] = 0;
    unsigned short* q = xlo + (size_t)row * kXStride + kIn;
    q[g] = 0; q[16 + g] = 0; q[32 + g] = 0; q[48 + g] = 0;
  }
}

// ---------------- grouped GEMM ----------------
__global__ __launch_bounds__(256, 2) void hqq_gemm(
    const unsigned short* __restrict__ xhi, const unsigned short* __restrict__ xlo,
    const int* __restrict__ wq, const float* __restrict__ scales,
    const float* __restrict__ zeros, const int* __restrict__ tpe,
    float* __restrict__ out) {
  __shared__ unsigned short Ahi[kBM * 64];   // 8 KB
  __shared__ unsigned short Alo[kBM * 64];   // 8 KB
  __shared__ unsigned short Bt[kBN * kBTS];  // 18 KB, [o][k] transposed

  const int bid = blockIdx.x;
  const int nt = bid >> 8;    // 0..21  (n-tile slow -> m-tiles of same panel adjacent)
  const int em = bid & 255;
  const int e = em >> 5;
  const int mt = em & 31;

  int e_start = 0, cnt = 0, cum = 0;
#pragma unroll
  for (int i = 0; i < kE; ++i) {
    int c = tpe[i];
    if (i == e) { e_start = cum; cnt = c; }
    cum += c;
  }
  if (mt * kBM >= cnt) return;  // empty (e,mtile) slot — block-uniform exit
  const int e_end = e_start + cnt;
  const int row0 = e_start + mt * kBM;
  const int nn = nt * kBN;

  const int tid = threadIdx.x;
  const int lane = tid & 63;
  const int wid = tid >> 6;  // 0..3
  const int wm = wid >> 1;   // wave row-half (32 rows)
  const int wn = wid & 1;    // wave col-half (64 cols)

  // ---- A staging: each wave issues 4 global_load_lds (2 hi + 2 lo) ----
  const int i0 = 2 * wid, i1 = 2 * wid + 1;  // 8-row slabs
  int r0 = row0 + 8 * i0 + (lane >> 3); if (r0 > kTok - 1) r0 = kTok - 1;
  int r1 = row0 + 8 * i1 + (lane >> 3); if (r1 > kTok - 1) r1 = kTok - 1;
  const int lchunk = (lane & 7) * 8;
  const unsigned short* sh0 = xhi + (size_t)r0 * kXStride + lchunk;
  const unsigned short* sh1 = xhi + (size_t)r1 * kXStride + lchunk;
  const unsigned short* sl0 = xlo + (size_t)r0 * kXStride + lchunk;
  const unsigned short* sl1 = xlo + (size_t)r1 * kXStride + lchunk;
  unsigned short* dh0 = Ahi + i0 * 512;
  unsigned short* dh1 = Ahi + i1 * 512;
  unsigned short* dl0 = Alo + i0 * 512;
  unsigned short* dl1 = Alo + i1 * 512;

  // ---- B staging: thread covers 8 k x 4 o (one unit) ----
  const int oq = tid & 31;   // o-quad
  const int kc = tid >> 5;   // k-chunk 0..7
  const int* wbase = wq + (size_t)e * kIn * kOut + (size_t)(kc * 8) * kOut + nn + oq * 4;
  unsigned short* btw = Bt + (oq * 4) * kBTS + kc * 8;

  const float* sc_base = scales + (size_t)e * kGroups * kOut + nn + wn * 64 + (lane & 15);

  f32x4 acc[2][4], S[2][4];
#pragma unroll
  for (int a = 0; a < 2; ++a)
#pragma unroll
    for (int b = 0; b < 4; ++b) { acc[a][b] = 0.f; S[a][b] = 0.f; }

  auto compute_tile = [&](const float* sc) {
#pragma unroll
    for (int ks = 0; ks < 2; ++ks) {
      const int k0 = ks * 32 + (lane >> 4) * 8;
      short8 ah[2], al[2], bb[4];
#pragma unroll
      for (int mf = 0; mf < 2; ++mf) {
        const int mrow = wm * 32 + mf * 16 + (lane & 15);
        ah[mf] = *(const short8*)&Ahi[mrow * 64 + k0];
        al[mf] = *(const short8*)&Alo[mrow * 64 + k0];
      }
#pragma unroll
      for (int nf = 0; nf < 4; ++nf) {
        const int nrow = wn * 64 + nf * 16 + (lane & 15);
        bb[nf] = *(const short8*)&Bt[nrow * kBTS + k0];
      }
#pragma unroll
      for (int mf = 0; mf < 2; ++mf)
#pragma unroll
        for (int nf = 0; nf < 4; ++nf) {
          S[mf][nf] = __builtin_amdgcn_mfma_f32_16x16x32_bf16(ah[mf], bb[nf], S[mf][nf], 0, 0, 0);
          S[mf][nf] = __builtin_amdgcn_mfma_f32_16x16x32_bf16(al[mf], bb[nf], S[mf][nf], 0, 0, 0);
        }
    }
    // fp32 per-group scale application, reset partials
#pragma unroll
    for (int mf = 0; mf < 2; ++mf)
#pragma unroll
      for (int nf = 0; nf < 4; ++nf) {
        acc[mf][nf] += sc[nf] * S[mf][nf];
        S[mf][nf] = 0.f;
      }
  };

  for (int g = 0; g < 16; ++g) {
    // B: 8x dwordx4 loads, int->bf16 (exact), transposed LDS writes
    i32x4 w[8];
    const int* p = wbase + (size_t)g * 64 * kOut;
#pragma unroll
    for (int i = 0; i < 8; ++i) w[i] = *(const i32x4*)(p + (size_t)i * kOut);
#pragma unroll
    for (int j = 0; j < 4; ++j) {
      u32x4 o;
#pragma unroll
      for (int ww = 0; ww < 4; ++ww) {
        uint32_t b0 = fbits((float)w[2 * ww][j]);      // k = 2*ww   (low 16)
        uint32_t b1 = fbits((float)w[2 * ww + 1][j]);  // k = 2*ww+1 (high 16)
        o[ww] = (b0 >> 16) | (b1 & 0xffff0000u);
      }
      *(u32x4*)(btw + j * kBTS) = o;
    }
    // A: async global->LDS
    async_cp16(sh0 + g * 64, dh0);
    async_cp16(sh1 + g * 64, dh1);
    async_cp16(sl0 + g * 64, dl0);
    async_cp16(sl1 + g * 64, dl1);
    __syncthreads();  // drains vmcnt (gload_lds) + lgkm (ds_write)

    float sc[4];
#pragma unroll
    for (int nf = 0; nf < 4; ++nf) sc[nf] = sc_base[(size_t)g * kOut + nf * 16];
    compute_tile(sc);
    __syncthreads();  // protect LDS before next stage
  }

  // ---- pseudo group 16: zero-point correction via MFMA ----
  {
    const int o = tid >> 1;  // Bt row 0..127
    const int h = tid & 1;
    const float* zp = zeros + (size_t)e * kGroups * kOut + nn + o;
    const float* sp = scales + (size_t)e * kGroups * kOut + nn + o;
    unsigned short zh[16], zl[16];
#pragma unroll
    for (int gg = 0; gg < 16; ++gg) {
      float zsv = -(zp[(size_t)gg * kOut] * sp[(size_t)gg * kOut]);
      unsigned short hh = bf16_rne(zsv);
      zh[gg] = hh;
      zl[gg] = bf16_rne(zsv - bf16_f(hh));
    }
    unsigned short* wrow = Bt + o * kBTS;
    auto pack8 = [](const unsigned short* u) {
      u32x4 r;
#pragma unroll
      for (int ww = 0; ww < 4; ++ww) r[ww] = (uint32_t)u[2 * ww] | ((uint32_t)u[2 * ww + 1] << 16);
      return r;
    };
    if (h == 0) {  // k-cols 0..31: [-zs_hi | -zs_lo]
      *(u32x4*)(wrow + 0)  = pack8(zh);
      *(u32x4*)(wrow + 8)  = pack8(zh + 8);
      *(u32x4*)(wrow + 16) = pack8(zl);
      *(u32x4*)(wrow + 24) = pack8(zl + 8);
    } else {       // k-cols 32..63: [-zs_hi | 0]
      *(u32x4*)(wrow + 32) = pack8(zh);
      *(u32x4*)(wrow + 40) = pack8(zh + 8);
      u32x4 z; z[0] = z[1] = z[2] = z[3] = 0;
      *(u32x4*)(wrow + 48) = z;
      *(u32x4*)(wrow + 56) = z;
    }
    async_cp16(sh0 + 16 * 64, dh0);  // A pseudo cols 1024..1087 (xlo plane is 0 there)
    async_cp16(sh1 + 16 * 64, dh1);
    async_cp16(sl0 + 16 * 64, dl0);
    async_cp16(sl1 + 16 * 64, dl1);
    __syncthreads();
    const float sc1[4] = {1.f, 1.f, 1.f, 1.f};
    compute_tile(sc1);
  }

  // ---- epilogue: predicated fp32 stores ----
  float* ob = out + nn + wn * 64 + (lane & 15);
#pragma unroll
  for (int mf = 0; mf < 2; ++mf)
#pragma unroll
    for (int i = 0; i < 4; ++i) {
      const int t = row0 + wm * 32 + mf * 16 + (lane >> 4) * 4 + i;
      if (t < e_end) {
#pragma unroll
        for (int nf = 0; nf < 4; ++nf)
          ob[(size_t)t * kOut + nf * 16] = acc[mf][nf][i];
      }
    }
}

extern "C" void kernel_launch(void* const* d_in, const int* in_sizes, int n_in,
                              void* d_out, int out_size, void* d_ws, size_t ws_size,
                              hipStream_t stream) {
  const float* x = (const float*)d_in[0];
  const int* tpe = (const int*)d_in[1];
  const int* wq = (const int*)d_in[2];
  const float* scales = (const float*)d_in[3];
  const float* zeros = (const float*)d_in[4];
  float* out = (float*)d_out;

  // ws layout: xhi [2048*1088] bf16, xlo [2048*1088] bf16  (~8.9 MB total)
  unsigned short* xhi = (unsigned short*)d_ws;
  unsigned short* xlo = xhi + (size_t)kTok * kXStride;

  hqq_prep<<<dim3(kTok), dim3(256), 0, stream>>>(x, xhi, xlo);
  hqq_gemm<<<dim3(kNT * 256), dim3(256), 0, stream>>>(xhi, xlo, wq, scales, zeros, tpe, out);
}

// Round 2
// 266.497 us; speedup vs baseline: 1.7643x; 1.7643x over previous
//
#include <hip/hip_runtime.h>
#include <hip/hip_bf16.h>
#include <stdint.h>

// HQQ grouped GEMM, MI355X (gfx950) — round 2.
//   y[t,o] = sum_g scale[e,g,o] * (x_g @ Wq_g)[t,o] - sum_g r[t,g]*zero*scale
// x split into bf16 hi+lo planes (fp32-quality); Wq exact in bf16; zero-term
// folded as pseudo K-group 16 (A cols [r_hi|r_hi|r_lo|0], B rows
// [-zs_hi|-zs_lo|-zs_hi|0]).
//
// Round-2 changes (latency-bound fix, 355us @ MfmaUtil 3.2%):
//  - T3 2-phase pipeline: loadB(g+1) -> compute(g) -> cvt+write Bt[(g+1)&1]
//    -> barrier. B global latency hides under compute. Double-buffered B LDS.
//  - A fragments read DIRECTLY from global (L2/L3-resident, 8.9 MB, reused
//    22x; coalesced 64B row segments). Removes 16-way bank-conflicted A-LDS
//    reads (was 1.2e7 conflict cycles) + 32 KB LDS.
//  - T1 bijective XCD swizzle (5632 = 8*704): same-panel m-tiles share an
//    XCD L2 -> cut 262 MB HBM re-fetch toward the 92 MB Wq floor.

namespace {
constexpr int kE = 8;
constexpr int kIn = 1024;
constexpr int kOut = 2816;
constexpr int kGroups = 16;         // quant groups along IN (GS=64)
constexpr int kTok = 2048;
constexpr int kXStride = kIn + 64;  // 1088: x cols + pseudo-group cols
constexpr int kBM = 64;
constexpr int kBN = 128;
constexpr int kBTS = 72;            // Bt LDS row stride in elems (144 B, 16B-aligned)
constexpr int kNT = kOut / kBN;     // 22 n-tiles
constexpr int kGrid = kNT * 256;    // 5632 = 8 * 704
}

typedef __attribute__((ext_vector_type(8))) short short8;
typedef __attribute__((ext_vector_type(4))) float f32x4;
typedef __attribute__((ext_vector_type(4))) int i32x4;
typedef __attribute__((ext_vector_type(4))) unsigned int u32x4;

static __device__ __forceinline__ uint32_t fbits(float f) {
  union { float f; uint32_t u; } v; v.f = f; return v.u;
}
static __device__ __forceinline__ unsigned short bf16_rne(float f) {
  uint32_t u = fbits(f);
  u += 0x7fffu + ((u >> 16) & 1u);
  return (unsigned short)(u >> 16);
}
static __device__ __forceinline__ float bf16_f(unsigned short h) {
  union { uint32_t u; float f; } v; v.u = ((uint32_t)h) << 16; return v.f;
}

// ---------------- prep: x -> bf16 hi/lo planes + group rowsums ----------------
// (unchanged from round 1 — known good)
__global__ __launch_bounds__(256) void hqq_prep(const float* __restrict__ x,
                                                unsigned short* __restrict__ xhi,
                                                unsigned short* __restrict__ xlo) {
  const int row = blockIdx.x;   // token
  const int tid = threadIdx.x;  // 256 threads, 4 floats each
  const f32x4 v = *(const f32x4*)(x + (size_t)row * kIn + tid * 4);
  unsigned long long hp = 0, lp = 0;
  float s = 0.f;
#pragma unroll
  for (int j = 0; j < 4; ++j) {
    float f = v[j];
    unsigned short h = bf16_rne(f);
    unsigned short l = bf16_rne(f - bf16_f(h));
    hp |= ((unsigned long long)h) << (16 * j);
    lp |= ((unsigned long long)l) << (16 * j);
    s += f;
  }
  *(unsigned long long*)(xhi + (size_t)row * kXStride + tid * 4) = hp;
  *(unsigned long long*)(xlo + (size_t)row * kXStride + tid * 4) = lp;
  // group rowsum: 16 consecutive lanes = 64 floats = one group
#pragma unroll
  for (int m = 1; m <= 8; m <<= 1) s += __shfl_xor(s, m, 64);
  if ((tid & 15) == 0) {
    const int g = tid >> 4;  // 0..15
    unsigned short rhi = bf16_rne(s);
    unsigned short rlo = bf16_rne(s - bf16_f(rhi));
    unsigned short* p = xhi + (size_t)row * kXStride + kIn;
    p[g] = rhi; p[16 + g] = rhi; p[32 + g] = rlo; p[48 + g] = 0;
    unsigned short* q = xlo + (size_t)row * kXStride + kIn;
    q[g] = 0; q[16 + g] = 0; q[32 + g] = 0; q[48 + g] = 0;
  }
}

// ---------------- grouped GEMM ----------------
__global__ __launch_bounds__(256, 2) void hqq_gemm(
    const unsigned short* __restrict__ xhi, const unsigned short* __restrict__ xlo,
    const int* __restrict__ wq, const float* __restrict__ scales,
    const float* __restrict__ zeros, const int* __restrict__ tpe,
    float* __restrict__ out) {
  __shared__ unsigned short Bt[2][kBN * kBTS];  // 2 x 18 KB, [o][k] transposed

  // T1 XCD swizzle: 5632 blocks = 8 XCDs * 704. Consecutive logical ids
  // (same (e,nt) panel, adjacent m-tiles) land on one XCD's L2.
  const int raw = blockIdx.x;
  const int bid = (raw & 7) * (kGrid / 8) + (raw >> 3);

  const int nt = bid >> 8;    // 0..21
  const int em = bid & 255;
  const int e = em >> 5;
  const int mt = em & 31;

  int e_start = 0, cnt = 0, cum = 0;
#pragma unroll
  for (int i = 0; i < kE; ++i) {
    int c = tpe[i];
    if (i == e) { e_start = cum; cnt = c; }
    cum += c;
  }
  if (mt * kBM >= cnt) return;  // empty (e,mtile) slot — block-uniform exit
  const int e_end = e_start + cnt;
  const int row0 = e_start + mt * kBM;
  const int nn = nt * kBN;

  const int tid = threadIdx.x;
  const int lane = tid & 63;
  const int wid = tid >> 6;  // 0..3
  const int wm = wid >> 1;   // wave row-half (32 rows)
  const int wn = wid & 1;    // wave col-half (64 cols)

  // ---- A fragment row bases (global, clamped so partial tiles stay in-bounds)
  size_t arow[2];
#pragma unroll
  for (int mf = 0; mf < 2; ++mf) {
    int r = row0 + wm * 32 + mf * 16 + (lane & 15);
    if (r > kTok - 1) r = kTok - 1;
    arow[mf] = (size_t)r * kXStride;
  }

  // ---- B staging: thread covers 8 k x 4 o ----
  const int oq = tid & 31;   // o-quad
  const int kc = tid >> 5;   // k-chunk 0..7
  const int* wbase = wq + (size_t)e * kIn * kOut + (size_t)(kc * 8) * kOut + nn + oq * 4;
  const int btw_off = (oq * 4) * kBTS + kc * 8;

  const float* sc_base = scales + (size_t)e * kGroups * kOut + nn + wn * 64 + (lane & 15);

  i32x4 w[8];
  auto loadB = [&](int g) {
    const int* p = wbase + (size_t)g * 64 * kOut;
#pragma unroll
    for (int i = 0; i < 8; ++i) w[i] = *(const i32x4*)(p + (size_t)i * kOut);
  };
  auto writeB = [&](int buf) {
    unsigned short* btw = &Bt[buf][btw_off];
#pragma unroll
    for (int j = 0; j < 4; ++j) {
      u32x4 o;
#pragma unroll
      for (int ww = 0; ww < 4; ++ww) {
        uint32_t b0 = fbits((float)w[2 * ww][j]);      // k = 2*ww   (low 16)
        uint32_t b1 = fbits((float)w[2 * ww + 1][j]);  // k = 2*ww+1 (high 16)
        o[ww] = (b0 >> 16) | (b1 & 0xffff0000u);
      }
      *(u32x4*)(btw + j * kBTS) = o;
    }
  };

  f32x4 acc[2][4];
#pragma unroll
  for (int a = 0; a < 2; ++a)
#pragma unroll
    for (int b = 0; b < 4; ++b) acc[a][b] = 0.f;

  // ---- prologue: Bt[0] = B(0) ----
  loadB(0);
  writeB(0);
  __syncthreads();

  for (int g = 0; g <= 16; ++g) {
    if (g < 15) loadB(g + 1);  // prefetch next B into regs (flies during compute)

    float sc[4];
#pragma unroll
    for (int nf = 0; nf < 4; ++nf)
      sc[nf] = (g < kGroups) ? sc_base[(size_t)g * kOut + nf * 16] : 1.f;

    f32x4 S[2][4];
#pragma unroll
    for (int a = 0; a < 2; ++a)
#pragma unroll
      for (int b = 0; b < 4; ++b) S[a][b] = 0.f;

    const unsigned short* btb = &Bt[g & 1][0];
#pragma unroll
    for (int ks = 0; ks < 2; ++ks) {
      const int k0l = ks * 32 + (lane >> 4) * 8;   // LDS B col
      const int k0g = g * 64 + k0l;                // global A col
      short8 ah[2], al[2], bb[4];
#pragma unroll
      for (int mf = 0; mf < 2; ++mf) {
        ah[mf] = *(const short8*)&xhi[arow[mf] + k0g];
        al[mf] = *(const short8*)&xlo[arow[mf] + k0g];
      }
#pragma unroll
      for (int nf = 0; nf < 4; ++nf) {
        const int nrow = wn * 64 + nf * 16 + (lane & 15);
        bb[nf] = *(const short8*)&btb[nrow * kBTS + k0l];
      }
#pragma unroll
      for (int mf = 0; mf < 2; ++mf)
#pragma unroll
        for (int nf = 0; nf < 4; ++nf) {
          S[mf][nf] = __builtin_amdgcn_mfma_f32_16x16x32_bf16(ah[mf], bb[nf], S[mf][nf], 0, 0, 0);
          S[mf][nf] = __builtin_amdgcn_mfma_f32_16x16x32_bf16(al[mf], bb[nf], S[mf][nf], 0, 0, 0);
        }
    }
#pragma unroll
    for (int mf = 0; mf < 2; ++mf)
#pragma unroll
      for (int nf = 0; nf < 4; ++nf) acc[mf][nf] += sc[nf] * S[mf][nf];

    // ---- stage next tile into the other buffer ----
    if (g < 15) {
      writeB((g + 1) & 1);
    } else if (g == 15) {
      // pseudo group 16: B rows = [-zs_hi | -zs_lo | -zs_hi | 0] into Bt[0]
      const int o = tid >> 1;  // 0..127
      const int h = tid & 1;
      const float* zp = zeros + (size_t)e * kGroups * kOut + nn + o;
      const float* sp = scales + (size_t)e * kGroups * kOut + nn + o;
      unsigned short zh[16], zl[16];
#pragma unroll
      for (int gg = 0; gg < 16; ++gg) {
        float zsv = -(zp[(size_t)gg * kOut] * sp[(size_t)gg * kOut]);
        unsigned short hh = bf16_rne(zsv);
        zh[gg] = hh;
        zl[gg] = bf16_rne(zsv - bf16_f(hh));
      }
      unsigned short* wrow = &Bt[0][o * kBTS];
      auto pack8 = [](const unsigned short* u) {
        u32x4 r;
#pragma unroll
        for (int ww = 0; ww < 4; ++ww)
          r[ww] = (uint32_t)u[2 * ww] | ((uint32_t)u[2 * ww + 1] << 16);
        return r;
      };
      if (h == 0) {  // k 0..31: [-zs_hi | -zs_lo]
        *(u32x4*)(wrow + 0)  = pack8(zh);
        *(u32x4*)(wrow + 8)  = pack8(zh + 8);
        *(u32x4*)(wrow + 16) = pack8(zl);
        *(u32x4*)(wrow + 24) = pack8(zl + 8);
      } else {       // k 32..63: [-zs_hi | 0]
        *(u32x4*)(wrow + 32) = pack8(zh);
        *(u32x4*)(wrow + 40) = pack8(zh + 8);
        u32x4 z; z[0] = z[1] = z[2] = z[3] = 0;
        *(u32x4*)(wrow + 48) = z;
        *(u32x4*)(wrow + 56) = z;
      }
    }
    if (g < 16) __syncthreads();
  }

  // ---- epilogue: predicated fp32 stores ----
  float* ob = out + nn + wn * 64 + (lane & 15);
#pragma unroll
  for (int mf = 0; mf < 2; ++mf)
#pragma unroll
    for (int i = 0; i < 4; ++i) {
      const int t = row0 + wm * 32 + mf * 16 + (lane >> 4) * 4 + i;
      if (t < e_end) {
#pragma unroll
        for (int nf = 0; nf < 4; ++nf)
          ob[(size_t)t * kOut + nf * 16] = acc[mf][nf][i];
      }
    }
}

extern "C" void kernel_launch(void* const* d_in, const int* in_sizes, int n_in,
                              void* d_out, int out_size, void* d_ws, size_t ws_size,
                              hipStream_t stream) {
  const float* x = (const float*)d_in[0];
  const int* tpe = (const int*)d_in[1];
  const int* wq = (const int*)d_in[2];
  const float* scales = (const float*)d_in[3];
  const float* zeros = (const float*)d_in[4];
  float* out = (float*)d_out;

  // ws layout: xhi [2048*1088] bf16, xlo [2048*1088] bf16  (~8.9 MB total)
  unsigned short* xhi = (unsigned short*)d_ws;
  unsigned short* xlo = xhi + (size_t)kTok * kXStride;

  hqq_prep<<<dim3(kTok), dim3(256), 0, stream>>>(x, xhi, xlo);
  hqq_gemm<<<dim3(kGrid), dim3(256), 0, stream>>>(xhi, xlo, wq, scales, zeros, tpe, out);
}